// Round 16
// baseline (219.462 us; speedup 1.0000x reference)
//
#include <hip/hip_runtime.h>
#include <math.h>

#define PI_F 3.14159265358979323846f
#define KSTEP 0.21959209425992272f /* (log2(224)-1)/31 */

using bf16x8 = __attribute__((ext_vector_type(8))) short;
using f32x4 = __attribute__((ext_vector_type(4))) float;
using u16x8 = __attribute__((ext_vector_type(8))) unsigned short;

static __device__ __forceinline__ float wave_reduce_sum(float v) {
#pragma unroll
  for (int off = 32; off; off >>= 1) v += __shfl_down(v, off);
  return v;
}

static __device__ __forceinline__ unsigned short f2bf(float f) {
  unsigned u = __float_as_uint(f);
  return (unsigned short)((u + 0x7fffu + ((u >> 16) & 1u)) >> 16);
}

static __device__ __forceinline__ float bf2f(unsigned short s) {
  return __uint_as_float(((unsigned)s) << 16);
}

// ---- fused prep: x->bf16 x_t + t_mean | wk_bf (bf16 Wk rows, c-contig) | sc table ----
__global__ __launch_bounds__(256) void prep_kernel(const float* __restrict__ x,
                                                   const float* __restrict__ qkv_w,
                                                   unsigned short* __restrict__ xt,
                                                   float* __restrict__ t_mean,
                                                   unsigned short* __restrict__ wk_bf,
                                                   float2* __restrict__ sc) {
  const int bid = blockIdx.x;
  const int t = threadIdx.x;
  __shared__ float tile[64 * 33];
  if (bid < 1024) {
    const int ct = bid & 15, b = bid >> 4;
    const int cl = t >> 2, pq = (t & 3) * 8;  // read role
    const int pl = t >> 3, cq = (t & 7) * 8;  // write role
    float sum = 0.0f;
    const float* xrow = x + ((size_t)(b * 1024 + ct * 64 + cl) * 256) + pq;
    unsigned short* xtb = xt + (size_t)b * 262144 + ct * 64;
    for (int pt = 0; pt < 8; ++pt) {
      const float4 v0 = *reinterpret_cast<const float4*>(xrow + pt * 32);
      const float4 v1 = *reinterpret_cast<const float4*>(xrow + pt * 32 + 4);
      tile[cl * 33 + pq + 0] = v0.x; tile[cl * 33 + pq + 1] = v0.y;
      tile[cl * 33 + pq + 2] = v0.z; tile[cl * 33 + pq + 3] = v0.w;
      tile[cl * 33 + pq + 4] = v1.x; tile[cl * 33 + pq + 5] = v1.y;
      tile[cl * 33 + pq + 6] = v1.z; tile[cl * 33 + pq + 7] = v1.w;
      sum += (v0.x + v0.y) + (v0.z + v0.w) + (v1.x + v1.y) + (v1.z + v1.w);
      __syncthreads();
      u16x8 o;
#pragma unroll
      for (int e = 0; e < 8; ++e) o[e] = f2bf(tile[(cq + e) * 33 + pl]);
      *reinterpret_cast<u16x8*>(xtb + (size_t)(pt * 32 + pl) * 1024 + cq) = o;
      __syncthreads();
    }
    sum += __shfl_xor(sum, 1);
    sum += __shfl_xor(sum, 2);
    if ((t & 3) == 0) t_mean[b * 1024 + ct * 64 + cl] = sum * (1.0f / 256.0f);
  } else if (bid < 2048) {
    const int i = ((bid - 1024) * 256 + t) * 4;
    const float4 v = *reinterpret_cast<const float4*>(qkv_w + 1048576 + i);
    ushort4 r;
    r.x = f2bf(v.x); r.y = f2bf(v.y); r.z = f2bf(v.z); r.w = f2bf(v.w);
    *reinterpret_cast<ushort4*>(wk_bf + i) = r;
  } else {
    const int idx = (bid - 2048) * 256 + t;  // 16384
    const int m = idx >> 8, j = idx & 255;
    const float band = exp2f((float)(m & 31) * KSTEP) * PI_F;
    const float coord = (m < 32) ? (-1.0f + (2.0f / 15.0f) * (float)(j >> 4))
                                 : (-1.0f + (2.0f / 15.0f) * (float)(j & 15));
    float sn, cs;
    sincosf(coord * band, &sn, &cs);
    sc[idx] = make_float2(sn, cs);
  }
}

// ---------------- split-K skinny GEMM: Cp[kc] = A * B^T (K-chunk = 256) ----------------
__global__ __launch_bounds__(256) void gemm_splitk(
    const float* __restrict__ A, int lda, int aStrideZ,
    const float* __restrict__ B, int ldb, int bStrideZ,
    float* __restrict__ Cp, int ldc, int cStrideZ, int cStrideKc, int KC) {
  const int nt = blockIdx.x, mt = blockIdx.y;
  const int z = blockIdx.z / KC, kc = blockIdx.z % KC;
  const int tid = threadIdx.x;
  A += (size_t)z * aStrideZ + (size_t)mt * 32 * lda + kc * 256;
  B += (size_t)z * bStrideZ + (size_t)nt * 64 * ldb + kc * 256;
  Cp += (size_t)kc * cStrideKc + (size_t)z * cStrideZ + (size_t)mt * 32 * ldc + nt * 64;

  __shared__ float As[32][34];
  __shared__ float Bs[32][68];

  const int tm = tid >> 4;
  const int tn = tid & 15;
  float acc0[4] = {0, 0, 0, 0}, acc1[4] = {0, 0, 0, 0};

  for (int k0 = 0; k0 < 256; k0 += 32) {
    {
      const int m = tid >> 3, kq = tid & 7;
      float4 v = *reinterpret_cast<const float4*>(A + (size_t)m * lda + k0 + kq * 4);
      As[kq * 4 + 0][m] = v.x; As[kq * 4 + 1][m] = v.y;
      As[kq * 4 + 2][m] = v.z; As[kq * 4 + 3][m] = v.w;
    }
#pragma unroll
    for (int r = 0; r < 2; ++r) {
      const int idx = r * 256 + tid;
      const int n = idx >> 3, kq = idx & 7;
      float4 v = *reinterpret_cast<const float4*>(B + (size_t)n * ldb + k0 + kq * 4);
      Bs[kq * 4 + 0][n] = v.x; Bs[kq * 4 + 1][n] = v.y;
      Bs[kq * 4 + 2][n] = v.z; Bs[kq * 4 + 3][n] = v.w;
    }
    __syncthreads();
#pragma unroll
    for (int k = 0; k < 32; ++k) {
      const float a0 = As[k][tm * 2], a1 = As[k][tm * 2 + 1];
      const float4 bb = *reinterpret_cast<const float4*>(&Bs[k][tn * 4]);
      acc0[0] += a0 * bb.x; acc0[1] += a0 * bb.y; acc0[2] += a0 * bb.z; acc0[3] += a0 * bb.w;
      acc1[0] += a1 * bb.x; acc1[1] += a1 * bb.y; acc1[2] += a1 * bb.z; acc1[3] += a1 * bb.w;
    }
    __syncthreads();
  }
  *reinterpret_cast<float4*>(Cp + (size_t)(tm * 2) * ldc + tn * 4) =
      make_float4(acc0[0], acc0[1], acc0[2], acc0[3]);
  *reinterpret_cast<float4*>(Cp + (size_t)(tm * 2 + 1) * ldc + tn * 4) =
      make_float4(acc1[0], acc1[1], acc1[2], acc1[3]);
}

// ---------------- proj GEMM with inline 4-partial A reduce + Wv-bias ----------------
__global__ __launch_bounds__(256) void gemm_proj_splitk(
    const float* __restrict__ Apart, const float* __restrict__ abias,
    const float* __restrict__ B, float* __restrict__ Cp) {
  const int nt = blockIdx.x, mt = blockIdx.y, kc = blockIdx.z;
  const int tid = threadIdx.x;
  B += (size_t)nt * 64 * 1024 + kc * 256;
  Cp += (size_t)kc * 65536 + (size_t)mt * 32 * 1024 + nt * 64;

  __shared__ float As[32][34];
  __shared__ float Bs[32][68];

  const int tm = tid >> 4;
  const int tn = tid & 15;
  float acc0[4] = {0, 0, 0, 0}, acc1[4] = {0, 0, 0, 0};

  for (int k0 = 0; k0 < 256; k0 += 32) {
    {
      const int m = tid >> 3, kq = tid & 7;
      const int kg = kc * 256 + k0 + kq * 4;
      const float* Ab = Apart + (size_t)(mt * 32 + m) * 1024 + kg;
      float4 v = *reinterpret_cast<const float4*>(abias + kg);
#pragma unroll
      for (int r = 0; r < 4; ++r) {
        const float4 p = *reinterpret_cast<const float4*>(Ab + (size_t)r * 65536);
        v.x += p.x; v.y += p.y; v.z += p.z; v.w += p.w;
      }
      As[kq * 4 + 0][m] = v.x; As[kq * 4 + 1][m] = v.y;
      As[kq * 4 + 2][m] = v.z; As[kq * 4 + 3][m] = v.w;
    }
#pragma unroll
    for (int r = 0; r < 2; ++r) {
      const int idx = r * 256 + tid;
      const int n = idx >> 3, kq = idx & 7;
      float4 v = *reinterpret_cast<const float4*>(B + (size_t)n * 1024 + k0 + kq * 4);
      Bs[kq * 4 + 0][n] = v.x; Bs[kq * 4 + 1][n] = v.y;
      Bs[kq * 4 + 2][n] = v.z; Bs[kq * 4 + 3][n] = v.w;
    }
    __syncthreads();
#pragma unroll
    for (int k = 0; k < 32; ++k) {
      const float a0 = As[k][tm * 2], a1 = As[k][tm * 2 + 1];
      const float4 bb = *reinterpret_cast<const float4*>(&Bs[k][tn * 4]);
      acc0[0] += a0 * bb.x; acc0[1] += a0 * bb.y; acc0[2] += a0 * bb.z; acc0[3] += a0 * bb.w;
      acc1[0] += a1 * bb.x; acc1[1] += a1 * bb.y; acc1[2] += a1 * bb.z; acc1[3] += a1 * bb.w;
    }
    __syncthreads();
  }
  *reinterpret_cast<float4*>(Cp + (size_t)(tm * 2) * 1024 + tn * 4) =
      make_float4(acc0[0], acc0[1], acc0[2], acc0[3]);
  *reinterpret_cast<float4*>(Cp + (size_t)(tm * 2 + 1) * 1024 + tn * 4) =
      make_float4(acc1[0], acc1[1], acc1[2], acc1[3]);
}

// ---------------- reduce 4 split-K partials + bias ----------------
__global__ __launch_bounds__(256) void reduce4_bias(const float* __restrict__ part,
                                                    const float* __restrict__ bias,
                                                    float* __restrict__ out) {
  const int i = blockIdx.x * 256 + threadIdx.x;  // 65536
  out[i] = part[i] + part[i + 65536] + part[i + 131072] + part[i + 196608] + bias[i & 1023];
}

// ---------------- K-form scores + softmax + u (barrier-free streaming main loop) ----------------
// Block (b,h), 8 waves; wave owns 32 j. K[32j x 128d] = x_rows @ Wk_h^T via MFMA,
// operands loaded DIRECTLY to VGPRs (no LDS, no barriers). Epilogue: per-lane
// rotation via rqt table + 16-lane shfl reduce -> S; exact bias; softmax; u.
__global__ __launch_bounds__(512, 4) void scores_u(
    const unsigned short* __restrict__ wk, const unsigned short* __restrict__ xt,
    const float* __restrict__ q0p, const float* __restrict__ qkv_b,
    const float2* __restrict__ sc, const float* __restrict__ t_mean,
    float* __restrict__ u) {
  const int l = blockIdx.x;  // 512; same-b blocks share an XCD (l&7 = b&7)
  const int b = ((l >> 6) << 3) | (l & 7);
  const int h = (l >> 3) & 7;
  const int tid = threadIdx.x;
  const int w = tid >> 6, lane = tid & 63;
  const int col = lane & 15, rgrp = lane >> 4;

  __shared__ __align__(16) char smem[12544];
  // persist [0,2560) | rqt [2560,11008) [16][132] f32 | Sp [11264,12288)
  // up2 overlays rqt after softmax.
  float* persist = reinterpret_cast<float*>(smem);
  float* q0l = persist;          // [128]
  float* k0l = persist + 128;    // [128]
  float* biasg = persist + 256;  // [32]
  float* ps = persist + 288;     // [2]
  float* smax = persist + 290;   // [4]
  float* ssum = persist + 294;   // [4]
  float* attnl = persist + 298;  // [257]
  float* rqt = reinterpret_cast<float*>(smem + 2560);  // [16][132]
  float* Sp = reinterpret_cast<float*>(smem + 11264);  // [256]
  float* up2 = reinterpret_cast<float*>(smem + 2560);  // [2][1024] overlay

  const unsigned short* xtb = xt + (size_t)b * 262144;

  // prologue: q0/k0 reduce (head h)
  if (tid < 128) {
    const float* qp = q0p + (size_t)b * 2048 + h * 128 + tid;
    q0l[tid] = qkv_b[h * 128 + tid] + qp[0] + qp[131072] + qp[262144] + qp[393216];
    const float* kp = qp + 1024;
    k0l[tid] = qkv_b[1024 + h * 128 + tid] + kp[0] + kp[131072] + kp[262144] + kp[393216];
  }
  __syncthreads();

  // rqt[v][d]: rotated-q component d (halves: d<64 -> y-rep, d>=64 -> x-rep), grid idx v
  for (int i = tid; i < 2048; i += 512) {
    const int v = i >> 7, d = i & 127;
    const int s = d >> 6, dd = d & 63, p = dd >> 1;
    const int jrep = s ? v : v * 16;
    const float qe = q0l[s * 64 + 2 * p];
    const float qo = q0l[s * 64 + 2 * p + 1];
    const float2 tt = sc[(s * 32 + p) * 256 + jrep];
    rqt[v * 132 + d] = (dd & 1) ? (qo * tt.y - qe * tt.x) : (qe * tt.y + qo * tt.x);
  }
  __syncthreads();

  // ---- barrier-free K-GEMM: acc[mi][ni] = K[j-tile mi][d-tile ni]
  const unsigned short* ar0 = xtb + (size_t)(w * 32 + col) * 1024 + rgrp * 8;
  const unsigned short* ar1 = ar0 + 16 * 1024;
  const unsigned short* br = wk + ((size_t)h * 128 + col) * 1024 + rgrp * 8;

  f32x4 acc[2][8] = {};
  for (int t = 0; t < 16; ++t) {
#pragma unroll
    for (int kk = 0; kk < 2; ++kk) {
      const int off = t * 64 + kk * 32;
      const bf16x8 a0 = *reinterpret_cast<const bf16x8*>(ar0 + off);
      const bf16x8 a1 = *reinterpret_cast<const bf16x8*>(ar1 + off);
#pragma unroll
      for (int ni = 0; ni < 8; ++ni) {
        const bf16x8 bd = *reinterpret_cast<const bf16x8*>(br + (size_t)ni * 16384 + off);
        acc[0][ni] = __builtin_amdgcn_mfma_f32_16x16x32_bf16(a0, bd, acc[0][ni], 0, 0, 0);
        acc[1][ni] = __builtin_amdgcn_mfma_f32_16x16x32_bf16(a1, bd, acc[1][ni], 0, 0, 0);
      }
    }
  }

  // ---- rotate + reduce: S[j] = sum_d K[j,d] * rqt[sel(j,d)][d]
#pragma unroll
  for (int mi = 0; mi < 2; ++mi)
#pragma unroll
    for (int rr = 0; rr < 4; ++rr) {
      const int j = w * 32 + mi * 16 + rgrp * 4 + rr;
      const float* ry = rqt + (j >> 4) * 132;
      const float* rx = rqt + (j & 15) * 132;
      float s = 0.0f;
#pragma unroll
      for (int ni = 0; ni < 4; ++ni) s += acc[mi][ni][rr] * ry[ni * 16 + col];
#pragma unroll
      for (int ni = 4; ni < 8; ++ni) s += acc[mi][ni][rr] * rx[ni * 16 + col];
      s += __shfl_xor(s, 1);
      s += __shfl_xor(s, 2);
      s += __shfl_xor(s, 4);
      s += __shfl_xor(s, 8);
      if (col == 0) Sp[j] = s;
    }
  // exact bias: biasg[s*16+v] = rot_v(q0_half_s) . k_bias_half_s
  if (tid < 32) {
    const int s_ = tid >> 4, v_ = tid & 15;
    const float* bk = qkv_b + 1024 + h * 128 + s_ * 64;
    const int jrep = s_ ? v_ : v_ * 16;
    float a = 0.0f;
#pragma unroll 4
    for (int p = 0; p < 32; ++p) {
      const float qe = q0l[s_ * 64 + 2 * p];
      const float qo = q0l[s_ * 64 + 2 * p + 1];
      const float2 tt = sc[(s_ * 32 + p) * 256 + jrep];
      a += (qe * tt.y + qo * tt.x) * bk[2 * p] + (qo * tt.y - qe * tt.x) * bk[2 * p + 1];
    }
    biasg[tid] = a;
  }
  if (tid < 128) {
    float pr = q0l[tid] * k0l[tid];
    pr = wave_reduce_sum(pr);
    if (lane == 0) ps[w] = pr;
  }
  __syncthreads();

  // ---- softmax over 257 tokens (threads 0..255; tid0 also token 0)
  const float scale = 0.08838834764831845f;
  float ea = 0.0f, eb = 0.0f;
  if (tid < 256) {
    const float va = scale * (Sp[tid] + biasg[tid >> 4] + biasg[16 + (tid & 15)]);
    float vb = -3.0e38f;
    if (tid == 0) vb = scale * (ps[0] + ps[1]);
    float m0 = fmaxf(va, vb);
#pragma unroll
    for (int off = 32; off; off >>= 1) m0 = fmaxf(m0, __shfl_xor(m0, off));
    if (lane == 0) smax[w] = m0;
  }
  __syncthreads();
  if (tid < 256) {
    const float g0 = fmaxf(fmaxf(smax[0], smax[1]), fmaxf(smax[2], smax[3]));
    const float va = scale * (Sp[tid] + biasg[tid >> 4] + biasg[16 + (tid & 15)]);
    ea = expf(va - g0);
    if (tid == 0) eb = expf(scale * (ps[0] + ps[1]) - g0);
    float s0 = ea + eb;
#pragma unroll
    for (int off = 32; off; off >>= 1) s0 += __shfl_xor(s0, off);
    if (lane == 0) ssum[w] = s0;
  }
  __syncthreads();
  if (tid < 256) {
    const float inv = 1.0f / (ssum[0] + ssum[1] + ssum[2] + ssum[3]);
    attnl[1 + tid] = ea * inv;
    if (tid == 0) attnl[0] = eb * inv;
  }
  __syncthreads();

  // ---- u: wave w = (jh = w>>2, cq = w&3); lane owns 4 c; 128 j per wave
  {
    const int jh = w >> 2, cq = w & 3;
    const int c0 = cq * 256 + lane * 4;
    float ua[4] = {};
    const unsigned short* xr = xtb + c0;
    for (int jj = 0; jj < 128; ++jj) {
      const int j = jh * 128 + jj;
      const float a0 = attnl[1 + j];
      const ushort4 v = *reinterpret_cast<const ushort4*>(xr + (size_t)j * 1024);
      ua[0] += a0 * bf2f(v.x);
      ua[1] += a0 * bf2f(v.y);
      ua[2] += a0 * bf2f(v.z);
      ua[3] += a0 * bf2f(v.w);
    }
#pragma unroll
    for (int e = 0; e < 4; ++e) up2[jh * 1024 + c0 + e] = ua[e];
  }
  __syncthreads();
  if (tid < 256) {
#pragma unroll
    for (int r = 0; r < 4; ++r) {
      const int c = tid * 4 + r;  // 0..1023
      float s = up2[c] + up2[1024 + c];
      s += attnl[0] * t_mean[b * 1024 + c];
      u[((size_t)b * 8 + h) * 1024 + c] = s;
    }
  }
}

// ---------------- host side ----------------
extern "C" void kernel_launch(void* const* d_in, const int* in_sizes, int n_in,
                              void* d_out, int out_size, void* d_ws, size_t ws_size,
                              hipStream_t stream) {
  const float* x = (const float*)d_in[0];
  const float* qkv_w = (const float*)d_in[1];
  const float* qkv_b = (const float*)d_in[2];
  const float* proj_w = (const float*)d_in[3];
  const float* proj_b = (const float*)d_in[4];
  float* out = (float*)d_out;

  float* ws = (float*)d_ws;
  float* t_mean = ws;                                       // [0, 65536)
  float* q0k0_part = ws + 65536;                            // [65536, 589824)
  float* u = ws + 589824;                                   // [589824, 1114112)
  float* out0_part = ws + 1114112;                          // [1114112, 1376256)
  float* out_part = ws + 1376256;                           // [1376256, 1638400)
  float2* sc = (float2*)(ws + 1638400);                     // [1638400, 1671168)
  unsigned short* wk_bf = (unsigned short*)(ws + 1671168);  // 1048576 u16
  unsigned short* x_t = (unsigned short*)(ws + 11698176);   // 16777216 u16

  // 1. fused prep: x->x_t+mean (1024) | wk_bf convert (1024) | sc table (64)
  prep_kernel<<<2112, 256, 0, stream>>>(x, qkv_w, x_t, t_mean, wk_bf, sc);

  // 2. q0k0 partials: t_mean @ qkv_w[0:2048].T  (M=64,N=2048,K=4x256)
  gemm_splitk<<<dim3(32, 2, 4), 256, 0, stream>>>(t_mean, 1024, 0, qkv_w, 1024, 0,
                                                  q0k0_part, 2048, 0, 131072, 4);

  // 3. K-form scores + softmax + u  (512 blocks = (b,h), barrier-free streaming)
  scores_u<<<512, 512, 0, stream>>>(wk_bf, x_t, q0k0_part, qkv_b, sc, t_mean, u);

  // 4. out0 partials: per-head Wv_h . u  (Z=8, K=4x256)
  gemm_splitk<<<dim3(2, 2, 32), 256, 0, stream>>>(u, 8192, 1024,
                                                  qkv_w + (size_t)2048 * 1024, 1024, 131072,
                                                  out0_part, 1024, 128, 65536, 4);

  // 5. proj partials, A = reduce4(out0_part)+bias_v inline
  gemm_proj_splitk<<<dim3(16, 2, 4), 256, 0, stream>>>(out0_part, qkv_b + 2048, proj_w, out_part);

  // 6. final reduce + proj bias
  reduce4_bias<<<256, 256, 0, stream>>>(out_part, proj_b, out);
}

// Round 17
// 95.564 us; speedup vs baseline: 2.2965x; 2.2965x over previous
//
#include <hip/hip_runtime.h>
#include <math.h>

#define PI_F 3.14159265358979323846f
#define KSTEP 0.21959209425992272f /* (log2(224)-1)/31 */

using bf16x8 = __attribute__((ext_vector_type(8))) short;
using f32x4 = __attribute__((ext_vector_type(4))) float;
using u16x8 = __attribute__((ext_vector_type(8))) unsigned short;

static __device__ __forceinline__ float wave_reduce_sum(float v) {
#pragma unroll
  for (int off = 32; off; off >>= 1) v += __shfl_down(v, off);
  return v;
}

static __device__ __forceinline__ unsigned short f2bf(float f) {
  unsigned u = __float_as_uint(f);
  return (unsigned short)((u + 0x7fffu + ((u >> 16) & 1u)) >> 16);
}

static __device__ __forceinline__ float bf2f(unsigned short s) {
  return __uint_as_float(((unsigned)s) << 16);
}

static __device__ __forceinline__ void gload_lds16(const void* g, void* l) {
  __builtin_amdgcn_global_load_lds((const __attribute__((address_space(1))) unsigned int*)g,
                                   (__attribute__((address_space(3))) unsigned int*)l, 16, 0, 0);
}

// ---- fused prep: x->bf16 x_t + t_mean | wkT (transposed Wk) | sc table ----
__global__ __launch_bounds__(256) void prep_kernel(const float* __restrict__ x,
                                                   const float* __restrict__ qkv_w,
                                                   const float* __restrict__ qkv_b,
                                                   unsigned short* __restrict__ xt,
                                                   float* __restrict__ t_mean,
                                                   unsigned short* __restrict__ wkT,
                                                   float2* __restrict__ sc) {
  const int bid = blockIdx.x;
  const int t = threadIdx.x;
  __shared__ float tile[64 * 33];
  __shared__ float tl2[64 * 65];
  if (bid < 1024) {
    const int ct = bid & 15, b = bid >> 4;
    const int cl = t >> 2, pq = (t & 3) * 8;  // read role
    const int pl = t >> 3, cq = (t & 7) * 8;  // write role
    float sum = 0.0f;
    const float* xrow = x + ((size_t)(b * 1024 + ct * 64 + cl) * 256) + pq;
    unsigned short* xtb = xt + (size_t)b * 262144 + ct * 64;
    for (int pt = 0; pt < 8; ++pt) {
      const float4 v0 = *reinterpret_cast<const float4*>(xrow + pt * 32);
      const float4 v1 = *reinterpret_cast<const float4*>(xrow + pt * 32 + 4);
      tile[cl * 33 + pq + 0] = v0.x; tile[cl * 33 + pq + 1] = v0.y;
      tile[cl * 33 + pq + 2] = v0.z; tile[cl * 33 + pq + 3] = v0.w;
      tile[cl * 33 + pq + 4] = v1.x; tile[cl * 33 + pq + 5] = v1.y;
      tile[cl * 33 + pq + 6] = v1.z; tile[cl * 33 + pq + 7] = v1.w;
      sum += (v0.x + v0.y) + (v0.z + v0.w) + (v1.x + v1.y) + (v1.z + v1.w);
      __syncthreads();
      u16x8 o;
#pragma unroll
      for (int e = 0; e < 8; ++e) o[e] = f2bf(tile[(cq + e) * 33 + pl]);
      *reinterpret_cast<u16x8*>(xtb + (size_t)(pt * 32 + pl) * 1024 + cq) = o;
      __syncthreads();
    }
    sum += __shfl_xor(sum, 1);
    sum += __shfl_xor(sum, 2);
    if ((t & 3) == 0) t_mean[b * 1024 + ct * 64 + cl] = sum * (1.0f / 256.0f);
  } else if (bid < 1280) {
    // wkT[h][c][d] transpose tiles: bf16, c rows, d contiguous
    const int bb = bid - 1024;
    const int h = bb >> 5, t5 = bb & 31;
    const int dt = t5 >> 4, ct = t5 & 15;
    {
      const int dl = t >> 2, cq = (t & 3) * 16;
      const float* src = qkv_w + (size_t)(1024 + h * 128 + dt * 64 + dl) * 1024 + ct * 64 + cq;
#pragma unroll
      for (int i = 0; i < 4; ++i) {
        const float4 v = *reinterpret_cast<const float4*>(src + i * 4);
        tl2[dl * 65 + cq + i * 4 + 0] = v.x; tl2[dl * 65 + cq + i * 4 + 1] = v.y;
        tl2[dl * 65 + cq + i * 4 + 2] = v.z; tl2[dl * 65 + cq + i * 4 + 3] = v.w;
      }
    }
    __syncthreads();
    {
      const int cl = t >> 2, dq = (t & 3) * 16;
      unsigned short* dst = wkT + (size_t)(h * 1152 + ct * 64 + cl) * 128 + dt * 64 + dq;
      u16x8 o0, o1;
#pragma unroll
      for (int e = 0; e < 8; ++e) {
        o0[e] = f2bf(tl2[(dq + e) * 65 + cl]);
        o1[e] = f2bf(tl2[(dq + 8 + e) * 65 + cl]);
      }
      *reinterpret_cast<u16x8*>(dst) = o0;
      *reinterpret_cast<u16x8*>(dst + 8) = o1;
    }
  } else {
    const int idx = (bid - 1280) * 256 + t;  // 16384
    const int m = idx >> 8, j = idx & 255;
    const float band = exp2f((float)(m & 31) * KSTEP) * PI_F;
    const float coord = (m < 32) ? (-1.0f + (2.0f / 15.0f) * (float)(j >> 4))
                                 : (-1.0f + (2.0f / 15.0f) * (float)(j & 15));
    float sn, cs;
    sincosf(coord * band, &sn, &cs);
    sc[idx] = make_float2(sn, cs);
  }
}

// ---------------- split-K skinny GEMM: Cp[kc] = A * B^T (K-chunk = 256) ----------------
__global__ __launch_bounds__(256) void gemm_splitk(
    const float* __restrict__ A, int lda, int aStrideZ,
    const float* __restrict__ B, int ldb, int bStrideZ,
    float* __restrict__ Cp, int ldc, int cStrideZ, int cStrideKc, int KC) {
  const int nt = blockIdx.x, mt = blockIdx.y;
  const int z = blockIdx.z / KC, kc = blockIdx.z % KC;
  const int tid = threadIdx.x;
  A += (size_t)z * aStrideZ + (size_t)mt * 32 * lda + kc * 256;
  B += (size_t)z * bStrideZ + (size_t)nt * 64 * ldb + kc * 256;
  Cp += (size_t)kc * cStrideKc + (size_t)z * cStrideZ + (size_t)mt * 32 * ldc + nt * 64;

  __shared__ float As[32][34];
  __shared__ float Bs[32][68];

  const int tm = tid >> 4;
  const int tn = tid & 15;
  float acc0[4] = {0, 0, 0, 0}, acc1[4] = {0, 0, 0, 0};

  for (int k0 = 0; k0 < 256; k0 += 32) {
    {
      const int m = tid >> 3, kq = tid & 7;
      float4 v = *reinterpret_cast<const float4*>(A + (size_t)m * lda + k0 + kq * 4);
      As[kq * 4 + 0][m] = v.x; As[kq * 4 + 1][m] = v.y;
      As[kq * 4 + 2][m] = v.z; As[kq * 4 + 3][m] = v.w;
    }
#pragma unroll
    for (int r = 0; r < 2; ++r) {
      const int idx = r * 256 + tid;
      const int n = idx >> 3, kq = idx & 7;
      float4 v = *reinterpret_cast<const float4*>(B + (size_t)n * ldb + k0 + kq * 4);
      Bs[kq * 4 + 0][n] = v.x; Bs[kq * 4 + 1][n] = v.y;
      Bs[kq * 4 + 2][n] = v.z; Bs[kq * 4 + 3][n] = v.w;
    }
    __syncthreads();
#pragma unroll
    for (int k = 0; k < 32; ++k) {
      const float a0 = As[k][tm * 2], a1 = As[k][tm * 2 + 1];
      const float4 bb = *reinterpret_cast<const float4*>(&Bs[k][tn * 4]);
      acc0[0] += a0 * bb.x; acc0[1] += a0 * bb.y; acc0[2] += a0 * bb.z; acc0[3] += a0 * bb.w;
      acc1[0] += a1 * bb.x; acc1[1] += a1 * bb.y; acc1[2] += a1 * bb.z; acc1[3] += a1 * bb.w;
    }
    __syncthreads();
  }
  *reinterpret_cast<float4*>(Cp + (size_t)(tm * 2) * ldc + tn * 4) =
      make_float4(acc0[0], acc0[1], acc0[2], acc0[3]);
  *reinterpret_cast<float4*>(Cp + (size_t)(tm * 2 + 1) * ldc + tn * 4) =
      make_float4(acc1[0], acc1[1], acc1[2], acc1[3]);
}

// ---------------- proj GEMM with inline 4-partial A reduce + Wv-bias ----------------
__global__ __launch_bounds__(256) void gemm_proj_splitk(
    const float* __restrict__ Apart, const float* __restrict__ abias,
    const float* __restrict__ B, float* __restrict__ Cp) {
  const int nt = blockIdx.x, mt = blockIdx.y, kc = blockIdx.z;
  const int tid = threadIdx.x;
  B += (size_t)nt * 64 * 1024 + kc * 256;
  Cp += (size_t)kc * 65536 + (size_t)mt * 32 * 1024 + nt * 64;

  __shared__ float As[32][34];
  __shared__ float Bs[32][68];

  const int tm = tid >> 4;
  const int tn = tid & 15;
  float acc0[4] = {0, 0, 0, 0}, acc1[4] = {0, 0, 0, 0};

  for (int k0 = 0; k0 < 256; k0 += 32) {
    {
      const int m = tid >> 3, kq = tid & 7;
      const int kg = kc * 256 + k0 + kq * 4;
      const float* Ab = Apart + (size_t)(mt * 32 + m) * 1024 + kg;
      float4 v = *reinterpret_cast<const float4*>(abias + kg);
#pragma unroll
      for (int r = 0; r < 4; ++r) {
        const float4 p = *reinterpret_cast<const float4*>(Ab + (size_t)r * 65536);
        v.x += p.x; v.y += p.y; v.z += p.z; v.w += p.w;
      }
      As[kq * 4 + 0][m] = v.x; As[kq * 4 + 1][m] = v.y;
      As[kq * 4 + 2][m] = v.z; As[kq * 4 + 3][m] = v.w;
    }
#pragma unroll
    for (int r = 0; r < 2; ++r) {
      const int idx = r * 256 + tid;
      const int n = idx >> 3, kq = idx & 7;
      float4 v = *reinterpret_cast<const float4*>(B + (size_t)n * 1024 + k0 + kq * 4);
      Bs[kq * 4 + 0][n] = v.x; Bs[kq * 4 + 1][n] = v.y;
      Bs[kq * 4 + 2][n] = v.z; Bs[kq * 4 + 3][n] = v.w;
    }
    __syncthreads();
#pragma unroll
    for (int k = 0; k < 32; ++k) {
      const float a0 = As[k][tm * 2], a1 = As[k][tm * 2 + 1];
      const float4 bb = *reinterpret_cast<const float4*>(&Bs[k][tn * 4]);
      acc0[0] += a0 * bb.x; acc0[1] += a0 * bb.y; acc0[2] += a0 * bb.z; acc0[3] += a0 * bb.w;
      acc1[0] += a1 * bb.x; acc1[1] += a1 * bb.y; acc1[2] += a1 * bb.z; acc1[3] += a1 * bb.w;
    }
    __syncthreads();
  }
  *reinterpret_cast<float4*>(Cp + (size_t)(tm * 2) * 1024 + tn * 4) =
      make_float4(acc0[0], acc0[1], acc0[2], acc0[3]);
  *reinterpret_cast<float4*>(Cp + (size_t)(tm * 2 + 1) * 1024 + tn * 4) =
      make_float4(acc1[0], acc1[1], acc1[2], acc1[3]);
}

// ---------------- reduce 4 split-K partials + bias ----------------
__global__ __launch_bounds__(256) void reduce4_bias(const float* __restrict__ part,
                                                    const float* __restrict__ bias,
                                                    float* __restrict__ out) {
  const int i = blockIdx.x * 256 + threadIdx.x;  // 65536
  out[i] = part[i] + part[i + 65536] + part[i + 131072] + part[i + 196608] + bias[i & 1023];
}

// ---------------- MFMA scores + fused T-gen + softmax + u ----------------
// Block (b, ht): per c-chunk (BK=64): stage x_t A-panel + wkT chunk; generate
// B-tile = rotq @ wkT_chunk^T in-block (MFMA, bf16); main P-GEMM; then diag
// extraction + exact bias + softmax + u. No T round-trip to HBM.
__global__ __launch_bounds__(512, 1) void scores_u(
    const unsigned short* __restrict__ wkT, const unsigned short* __restrict__ xt,
    const float* __restrict__ q0p, const float* __restrict__ qkv_b,
    const float2* __restrict__ sc, const float* __restrict__ t_mean,
    float* __restrict__ u) {
  const int l = blockIdx.x;  // 256; same-b blocks share an XCD (l&7 preserved)
  const int b = ((l >> 5) << 3) | (l & 7);
  const int ht = (l >> 3) & 3;  // head pair: heads ht*2, ht*2+1
  const int tid = threadIdx.x;
  const int w = tid >> 6, lane = tid & 63;
  const int rgrp = lane >> 4;

  // B-gen wave roles: combo kap = hh*2+s, c-half ch
  const int hh_ = w >> 2, sgen = (w >> 1) & 1, ch = w & 1;
  const int kap = hh_ * 2 + sgen;

  __shared__ __align__(16) char smem[143872];
  // [0,65536): A bufs (2 x 32KB, x_t)   [65536,131072): W bufs (2 x 32KB, wkT)
  // [131072,139264): Btile (64n x 128B)  [139264,...): persist
  float* persist = reinterpret_cast<float*>(smem + 139264);
  float* q0l = persist;          // [256]
  float* k0l = persist + 256;    // [256]
  float* biasg = persist + 512;  // [64]
  float* ps = persist + 576;     // [4]
  float* smax = persist + 580;   // [8]
  float* ssum = persist + 588;   // [8]
  float* attnl = persist + 596;  // [2][257]
  char* Btile = smem + 131072;

  const unsigned short* xtb = xt + (size_t)b * 262144;

#define STAGE_A(buf, c0)                                                        \
  {                                                                             \
    char* Ab_ = smem + (buf)*32768;                                             \
    _Pragma("unroll") for (int i = 0; i < 4; ++i) {                             \
      const int row_ = w * 32 + i * 8 + (lane >> 3);                            \
      const int sl_ = ((lane & 7) ^ ((row_ >> 1) & 7)) * 8;                     \
      gload_lds16(xtb + (size_t)row_ * 1024 + (c0) + sl_,                       \
                  Ab_ + (w * 4 + i) * 1024);                                    \
    }                                                                           \
  }
#define STAGE_W(buf, c0)                                                        \
  {                                                                             \
    char* Wb_ = smem + 65536 + (buf)*32768;                                     \
    _Pragma("unroll") for (int i = 0; i < 4; ++i) {                             \
      const int r_ = w * 16 + i * 4 + (lane >> 4); /* h*64+c */                 \
      const int c_ = r_ & 63;                                                   \
      const int L_ = lane & 15;                                                 \
      const int so_ = (L_ >> 3) * 64 + ((L_ & 7) ^ ((c_ >> 1) & 7)) * 8;        \
      gload_lds16(wkT + ((size_t)(ht * 2 + (r_ >> 6)) * 1152 + (c0) + c_) * 128 \
                      + so_,                                                    \
                  Wb_ + (w * 16 + i * 4) * 256);                                \
    }                                                                           \
  }

  // prologue: stage tile 0; q0/k0 reduce; rotq registers
  STAGE_A(0, 0);
  STAGE_W(0, 0);
  if (tid < 256) {
    const float* qp = q0p + (size_t)b * 2048 + ht * 256 + tid;
    q0l[tid] = qkv_b[ht * 256 + tid] + qp[0] + qp[131072] + qp[262144] + qp[393216];
    const float* kp = qp + 1024;
    k0l[tid] = qkv_b[1024 + ht * 256 + tid] + kp[0] + kp[131072] + kp[262144] + kp[393216];
  }
  __syncthreads();  // q0l visible; drains prologue gloads (ok, once)

  // rotq fragments in registers: rq[kk][e] = rot(v=lane&15, d=kk*32+rgrp*8+e)
  bf16x8 rq[2];
  {
    const int v = lane & 15;
    const int jrep = sgen ? v : v * 16;
#pragma unroll
    for (int kk = 0; kk < 2; ++kk) {
#pragma unroll
      for (int e = 0; e < 8; e += 2) {
        const int d = kk * 32 + rgrp * 8 + e;
        const int p = d >> 1;
        const float qe = q0l[hh_ * 128 + sgen * 64 + 2 * p];
        const float qo = q0l[hh_ * 128 + sgen * 64 + 2 * p + 1];
        const float2 tt = sc[(sgen * 32 + p) * 256 + jrep];
        rq[kk][e] = (short)f2bf(qe * tt.y + qo * tt.x);
        rq[kk][e + 1] = (short)f2bf(qo * tt.y - qe * tt.x);
      }
    }
  }

  f32x4 acc[2][4] = {};
  for (int t = 0; t < 16; ++t) {
    {  // stage tile t+1 (clamped tail keeps vmcnt uniform)
      const int src = (t + 1 > 15) ? 15 : (t + 1);
      STAGE_A((t + 1) & 1, src * 64);
      STAGE_W((t + 1) & 1, src * 64);
    }
    asm volatile("s_waitcnt vmcnt(8)" ::: "memory");  // tile t resident
    __builtin_amdgcn_s_barrier();
    const char* Ab = smem + (t & 1) * 32768;
    const char* Wb = smem + 65536 + (t & 1) * 32768;
    // ---- B-gen: Btile[n= kap*16+v][c] = sum_d wkT[c][d] * rotq[n][d]
    {
      f32x4 accg[2] = {};
#pragma unroll
      for (int kk = 0; kk < 2; ++kk) {
#pragma unroll
        for (int mt = 0; mt < 2; ++mt) {
          const int c_ = ch * 32 + mt * 16 + (lane & 15);
          const int slot = sgen * 8 + (((kk * 4 + rgrp)) ^ ((c_ >> 1) & 7));
          const bf16x8 wf = *reinterpret_cast<const bf16x8*>(
              Wb + (hh_ * 64 + c_) * 256 + (slot << 4));
          accg[mt] = __builtin_amdgcn_mfma_f32_16x16x32_bf16(wf, rq[kk], accg[mt], 0, 0, 0);
        }
      }
#pragma unroll
      for (int mt = 0; mt < 2; ++mt) {
        const int cl = ch * 32 + mt * 16 + rgrp * 4;
        const int n = kap * 16 + (lane & 15);
        const unsigned u0 = (unsigned)f2bf(accg[mt][0]) | ((unsigned)f2bf(accg[mt][1]) << 16);
        const unsigned u1 = (unsigned)f2bf(accg[mt][2]) | ((unsigned)f2bf(accg[mt][3]) << 16);
        *reinterpret_cast<uint2*>(Btile + n * 128 + ((((cl >> 3) ^ ((n >> 1) & 7))) << 4) +
                                  (rgrp & 1) * 8) = make_uint2(u0, u1);
      }
    }
    asm volatile("s_waitcnt lgkmcnt(0)" ::: "memory");
    __builtin_amdgcn_s_barrier();  // Btile ready
    // ---- main P-GEMM
#pragma unroll
    for (int kk = 0; kk < 2; ++kk) {
      bf16x8 af[2], bfr[4];
#pragma unroll
      for (int mi = 0; mi < 2; ++mi) {
        const int row = w * 32 + mi * 16 + (lane & 15);
        const int slot = (kk * 4 + rgrp) ^ ((row >> 1) & 7);
        af[mi] = *reinterpret_cast<const bf16x8*>(Ab + row * 128 + (slot << 4));
      }
#pragma unroll
      for (int ni = 0; ni < 4; ++ni) {
        const int n = ni * 16 + (lane & 15);
        const int slot = (kk * 4 + rgrp) ^ ((n >> 1) & 7);
        bfr[ni] = *reinterpret_cast<const bf16x8*>(Btile + n * 128 + (slot << 4));
      }
      __builtin_amdgcn_s_setprio(1);
#pragma unroll
      for (int mi = 0; mi < 2; ++mi)
#pragma unroll
        for (int ni = 0; ni < 4; ++ni)
          acc[mi][ni] =
              __builtin_amdgcn_mfma_f32_16x16x32_bf16(af[mi], bfr[ni], acc[mi][ni], 0, 0, 0);
      __builtin_amdgcn_s_setprio(0);
    }
    __builtin_amdgcn_s_barrier();  // readers done before next iter overwrites
    asm volatile("" ::: "memory");
  }
#undef STAGE_A
#undef STAGE_W

  asm volatile("s_waitcnt vmcnt(0)" ::: "memory");
  __syncthreads();

  // ---- epilogue arrays (reuse low LDS) ----
  float* Sp = reinterpret_cast<float*>(smem);  // [256 j][2 h][2 s]
  float* upart = reinterpret_cast<float*>(smem + 16384);  // [4 w][2 h][1024 c]

  // diagonal extraction: each (j, h, s) slot has exactly one writer lane
#pragma unroll
  for (int mi = 0; mi < 2; ++mi)
#pragma unroll
    for (int ni = 0; ni < 4; ++ni)
#pragma unroll
      for (int rr = 0; rr < 4; ++rr) {
        const int j = w * 32 + mi * 16 + (rgrp << 2) + rr;
        const int col = ni * 16 + (lane & 15);
        const int s = (col >> 4) & 1;
        const int sel = s ? (j & 15) : (j >> 4);
        if ((col & 15) == sel) Sp[(j * 2 + (col >> 5)) * 2 + s] = acc[mi][ni][rr];
      }
  // exact bias: biasg[h*32+s*16+v] = rot_v(q0_half) . k_bias_half
  if (tid < 64) {
    const int h_ = tid >> 5, s_ = (tid >> 4) & 1, v_ = tid & 15;
    const float* bk = qkv_b + 1024 + (ht * 2 + h_) * 128 + s_ * 64;
    const int jrep = s_ ? v_ : v_ * 16;
    float a = 0.0f;
#pragma unroll 4
    for (int p = 0; p < 32; ++p) {
      const float qe = q0l[h_ * 128 + s_ * 64 + 2 * p];
      const float qo = q0l[h_ * 128 + s_ * 64 + 2 * p + 1];
      const float2 tt = sc[(s_ * 32 + p) * 256 + jrep];
      a += (qe * tt.y + qo * tt.x) * bk[2 * p] + (qo * tt.y - qe * tt.x) * bk[2 * p + 1];
    }
    biasg[tid] = a;
  }
  if (tid < 256) {
    float pr = q0l[tid] * k0l[tid];
    pr = wave_reduce_sum(pr);
    if (lane == 0) ps[w] = pr;  // w 0,1 -> head0; 2,3 -> head1
  }
  __syncthreads();

  // ---- dual-head softmax over 257 tokens (threads 0..255; tid0 also token 0)
  const float scale = 0.08838834764831845f;
  float e0 = 0.0f, e1 = 0.0f, eb0 = 0.0f, eb1 = 0.0f;
  if (tid < 256) {
    const float va0 = scale * (Sp[tid * 4 + 0] + Sp[tid * 4 + 1] + biasg[tid >> 4] +
                               biasg[16 + (tid & 15)]);
    const float va1 = scale * (Sp[tid * 4 + 2] + Sp[tid * 4 + 3] + biasg[32 + (tid >> 4)] +
                               biasg[48 + (tid & 15)]);
    float vb0 = -3.0e38f, vb1 = -3.0e38f;
    if (tid == 0) {
      vb0 = scale * (ps[0] + ps[1]);
      vb1 = scale * (ps[2] + ps[3]);
    }
    float m0 = fmaxf(va0, vb0), m1 = fmaxf(va1, vb1);
#pragma unroll
    for (int off = 32; off; off >>= 1) {
      m0 = fmaxf(m0, __shfl_xor(m0, off));
      m1 = fmaxf(m1, __shfl_xor(m1, off));
    }
    if (lane == 0) { smax[w] = m0; smax[4 + w] = m1; }
  }
  __syncthreads();
  if (tid < 256) {
    const float g0 = fmaxf(fmaxf(smax[0], smax[1]), fmaxf(smax[2], smax[3]));
    const float g1 = fmaxf(fmaxf(smax[4], smax[5]), fmaxf(smax[6], smax[7]));
    const float va0 = scale * (Sp[tid * 4 + 0] + Sp[tid * 4 + 1] + biasg[tid >> 4] +
                               biasg[16 + (tid & 15)]);
    const float va1 = scale * (Sp[tid * 4 + 2] + Sp[tid * 4 + 3] + biasg[32 + (tid >> 4)] +
                               biasg[48 + (tid & 15)]);
    e0 = expf(va0 - g0);
    e1 = expf(va1 - g1);
    if (tid == 0) {
      eb0 = expf(scale * (ps[0] + ps[1]) - g0);
      eb1 = expf(scale * (ps[2] + ps[3]) - g1);
    }
    float s0 = e0 + eb0, s1 = e1 + eb1;
#pragma unroll
    for (int off = 32; off; off >>= 1) {
      s0 += __shfl_xor(s0, off);
      s1 += __shfl_xor(s1, off);
    }
    if (lane == 0) { ssum[w] = s0; ssum[4 + w] = s1; }
  }
  __syncthreads();
  if (tid < 256) {
    const float inv0 = 1.0f / (ssum[0] + ssum[1] + ssum[2] + ssum[3]);
    const float inv1 = 1.0f / (ssum[4] + ssum[5] + ssum[6] + ssum[7]);
    attnl[1 + tid] = e0 * inv0;
    attnl[257 + 1 + tid] = e1 * inv1;
    if (tid == 0) { attnl[0] = eb0 * inv0; attnl[257] = eb1 * inv1; }
  }
  __syncthreads();

  // ---- u: wave w accumulates its 32 j over all 1024 c (lane owns 16 c)
  {
    float ua0[16] = {}, ua1[16] = {};
    const unsigned short* xr = xtb + (size_t)(w * 32) * 1024 + lane * 16;
    for (int jj = 0; jj < 32; ++jj) {
      const float a0 = attnl[1 + w * 32 + jj];
      const float a1 = attnl[257 + 1 + w * 32 + jj];
      const u16x8 v0 = *reinterpret_cast<const u16x8*>(xr + (size_t)jj * 1024);
      const u16x8 v1 = *reinterpret_cast<const u16x8*>(xr + (size_t)jj * 1024 + 8);
#pragma unroll
      for (int e = 0; e < 8; ++e) {
        const float f0 = bf2f((unsigned short)v0[e]);
        const float f1 = bf2f((unsigned short)v1[e]);
        ua0[e] += a0 * f0; ua0[8 + e] += a0 * f1;
        ua1[e] += a1 * f0; ua1[8 + e] += a1 * f1;
      }
    }
#pragma unroll
    for (int e = 0; e < 16; ++e) {
      upart[(w * 2 + 0) * 1024 + lane * 16 + e] = ua0[e];
      upart[(w * 2 + 1) * 1024 + lane * 16 + e] = ua1[e];
    }
  }
  __syncthreads();
#pragma unroll
  for (int r = 0; r < 4; ++r) {
    const int o = tid * 4 + r;  // 0..2047
    const int h2 = o >> 10, c = o & 1023;
    float s = 0.0f;
#pragma unroll
    for (int ww = 0; ww < 8; ++ww) s += upart[(ww * 2 + h2) * 1024 + c];
    s += attnl[h2 * 257] * t_mean[b * 1024 + c];
    u[((size_t)b * 8 + ht * 2 + h2) * 1024 + c] = s;
  }
}

// ---------------- host side ----------------
extern "C" void kernel_launch(void* const* d_in, const int* in_sizes, int n_in,
                              void* d_out, int out_size, void* d_ws, size_t ws_size,
                              hipStream_t stream) {
  const float* x = (const float*)d_in[0];
  const float* qkv_w = (const float*)d_in[1];
  const float* qkv_b = (const float*)d_in[2];
  const float* proj_w = (const float*)d_in[3];
  const float* proj_b = (const float*)d_in[4];
  float* out = (float*)d_out;

  float* ws = (float*)d_ws;
  float* t_mean = ws;                                       // [0, 65536)
  float* q0k0_part = ws + 65536;                            // [65536, 589824)
  float* u = ws + 589824;                                   // [589824, 1114112)
  float* out0_part = ws + 1114112;                          // [1114112, 1376256)
  float* out_part = ws + 1376256;                           // [1376256, 1638400)
  float2* sc = (float2*)(ws + 1638400);                     // [1638400, 1671168)
  unsigned short* wkT = (unsigned short*)(ws + 1671168);    // 1179648 u16
  unsigned short* x_t = (unsigned short*)(ws + 11698176);   // 16777216 u16

  // 1. fused prep: x->x_t+mean (1024) | wkT transpose (256) | sc table (64)
  prep_kernel<<<1344, 256, 0, stream>>>(x, qkv_w, qkv_b, x_t, t_mean, wkT, sc);

  // 2. q0k0 partials: t_mean @ qkv_w[0:2048].T  (M=64,N=2048,K=4x256)
  gemm_splitk<<<dim3(32, 2, 4), 256, 0, stream>>>(t_mean, 1024, 0, qkv_w, 1024, 0,
                                                  q0k0_part, 2048, 0, 131072, 4);

  // 3. MFMA scores + in-block T-gen + softmax + u  (256 blocks, 8 waves)
  scores_u<<<256, 512, 0, stream>>>(wkT, x_t, q0k0_part, qkv_b, sc, t_mean, u);

  // 4. out0 partials: per-head Wv_h . u  (Z=8, K=4x256)
  gemm_splitk<<<dim3(2, 2, 32), 256, 0, stream>>>(u, 8192, 1024,
                                                  qkv_w + (size_t)2048 * 1024, 1024, 131072,
                                                  out0_part, 1024, 128, 65536, 4);

  // 5. proj partials, A = reduce4(out0_part)+bias_v inline
  gemm_proj_splitk<<<dim3(16, 2, 4), 256, 0, stream>>>(out0_part, qkv_b + 2048, proj_w, out_part);

  // 6. final reduce + proj bias
  reduce4_bias<<<256, 256, 0, stream>>>(out_part, proj_b, out);
}